// Round 8
// baseline (259.781 us; speedup 1.0000x reference)
//
#include <hip/hip_runtime.h>

#define MU 5
static constexpr int Hh = 1024, Ww = 1024, Bb = 8;
static constexpr int NPIX = Bb * Hh * Ww;
static constexpr int TPB = 256;
static constexpr int SPY = 4;
static constexpr int SOBEL_BLOCKS = NPIX / SPY / TPB;   // 8192

// fused V+H tile
static constexpr int TX = 64, TY = 32;
static constexpr int VW = TX + 2 * MU;        // 74 V-result cols
static constexpr int ER = TY + 2 * MU;        // 42 E rows
static constexpr int EPITCH = 76;             // padded E pitch (16B-aligned rows)
static constexpr int FBLK = (Ww / TX) * (Hh / TY) * Bb;   // 16*32*8 = 4096

__device__ __forceinline__ float rcp_fast(float x) { return __builtin_amdgcn_rcpf(x); }
__device__ __forceinline__ float rsq_fast(float x) { return __builtin_amdgcn_rsqf(x); }

// ---- Sobel: 4 rows per thread, shared row-differences, v_rsq ----
__global__ __launch_bounds__(TPB) void sobel_kernel(
        const float* __restrict__ in, float2* __restrict__ tang,
        float* __restrict__ mag, float* __restrict__ partials) {
    int id = blockIdx.x * TPB + threadIdx.x;
    int x = id & (Ww - 1);
    int yg = (id >> 10) & (Hh / SPY - 1);
    int b = id >> 18;
    int y0 = yg * SPY;
    const float* p = in + ((size_t)b << 20);

    float a[SPY + 2][3];
    bool cl = (x > 0), cr = (x < Ww - 1);
    if (yg >= 1 && yg <= Hh / SPY - 2) {
        #pragma unroll
        for (int r = 0; r < SPY + 2; ++r) {
            const float* row = p + (y0 - 1 + r) * Ww + x;
            a[r][0] = cl ? row[-1] : 0.0f;
            a[r][1] = row[0];
            a[r][2] = cr ? row[1] : 0.0f;
        }
    } else {
        #pragma unroll
        for (int r = 0; r < SPY + 2; ++r) {
            int yy = y0 - 1 + r;
            bool okr = (yy >= 0) && (yy < Hh);
            const float* row = p + (okr ? yy : 0) * Ww + x;
            a[r][0] = (okr && cl) ? row[-1] : 0.0f;
            a[r][1] = okr ? row[0] : 0.0f;
            a[r][2] = (okr && cr) ? row[1] : 0.0f;
        }
    }

    float s[SPY + 2];
    #pragma unroll
    for (int r = 0; r < SPY + 2; ++r) s[r] = a[r][2] - a[r][0];

    float vmax = 0.0f;
    #pragma unroll
    for (int k = 0; k < SPY; ++k) {
        float gx = s[k] + 2.0f * s[k + 1] + s[k + 2];
        float u1 = a[k + 2][0] - a[k][0];
        float u2 = a[k + 2][1] - a[k][1];
        float u3 = a[k + 2][2] - a[k][2];
        float gy = u1 + 2.0f * u2 + u3;
        float g2 = gx * gx + gy * gy;
        float irs = rsq_fast(g2);
        float m   = (g2 > 0.0f) ? g2 * irs : 0.0f;
        float inv = (g2 > 0.0f) ? irs : 1.0f;
        int j = (b << 20) + (y0 + k) * Ww + x;
        mag[j] = m;
        tang[j] = make_float2(-gy * inv, gx * inv);
        vmax = fmaxf(vmax, m);
    }

    #pragma unroll
    for (int off = 32; off; off >>= 1) vmax = fmaxf(vmax, __shfl_xor(vmax, off));
    __shared__ float smax[4];
    int lane = threadIdx.x & 63, wid = threadIdx.x >> 6;
    if (lane == 0) smax[wid] = vmax;
    __syncthreads();
    if (threadIdx.x == 0)
        partials[blockIdx.x] = fmaxf(fmaxf(smax[0], smax[1]), fmaxf(smax[2], smax[3]));
}

__global__ void max_reduce_kernel(const float* __restrict__ partials,
                                  float* __restrict__ scale_out) {
    float v = 0.0f;
    for (int i = threadIdx.x; i < SOBEL_BLOCKS; i += 1024)
        v = fmaxf(v, partials[i]);
    #pragma unroll
    for (int off = 32; off; off >>= 1) v = fmaxf(v, __shfl_xor(v, off));
    __shared__ float smax[16];
    int lane = threadIdx.x & 63, wid = threadIdx.x >> 6;
    if (lane == 0) smax[wid] = v;
    __syncthreads();
    if (threadIdx.x == 0) {
        float m = smax[0];
        #pragma unroll
        for (int i = 1; i < 16; ++i) m = fmaxf(m, smax[i]);
        *scale_out = 1.0f / m;
    }
}

// In-place: mag -> E = exp(2*scale*mag), E in [1, e^2].
// Per tap: (tanh(scale*(mY-mX))+1)*0.5 == E_Y / (E_X + E_Y).
__global__ void prep_kernel(float4* __restrict__ mag4,
                            const float* __restrict__ scalep) {
    int id = blockIdx.x * blockDim.x + threadIdx.x;
    float k = 2.0f * (*scalep);
    float4 m = mag4[id];
    m.x = __expf(k * m.x);
    m.y = __expf(k * m.y);
    m.z = __expf(k * m.z);
    m.w = __expf(k * m.w);
    mag4[id] = m;
}

// ---- Fused V+H iteration: 64x32 output tile per block ----
template <bool FINAL>
__global__ __launch_bounds__(TPB) void etf_fused(const float2* __restrict__ src,
                                                 float2* __restrict__ dstI,
                                                 float* __restrict__ dstP,
                                                 const float* __restrict__ E) {
    __shared__ float2 vT[TY][VW];       // 18,944 B: V results
    __shared__ float  eT[ER][EPITCH];   // 12,768 B: E tile

    int bid = (int)blockIdx.x;
    int swz = (bid & 7) * (FBLK / 8) + (bid >> 3);   // 512 tiles = 1 image/XCD
    int img = swz >> 9;
    int cid = swz & 511;
    int tx = cid >> 5, ty = cid & 31;   // column-major: vertical neighbors adjacent
    int x0 = tx * TX, y0 = ty * TY;
    int base = img << 20;
    int t = threadIdx.x;

    // ---- stage E tile (rows [y0-5,y0+37), cols [x0-5,x0+69)) ----
    for (int i = t; i < ER * VW; i += TPB) {
        int r = i / VW, c = i % VW;
        int gy = y0 - MU + r, gx = x0 - MU + c;
        bool ok = (gy >= 0) && (gy < Hh) && (gx >= 0) && (gx < Ww);
        eT[r][c] = ok ? E[base + gy * Ww + gx] : 1.0f;
    }
    __syncthreads();

    // ---- V phase: VW cols x TY/8 row-groups = 296 tasks ----
    for (int task = t; task < VW * (TY / 8); task += TPB) {
        int c = task % VW;          // 0..73
        int g = task / VW;          // 0..3
        int gx = x0 - MU + c;
        int yb = y0 + g * 8;
        if (gx < 0 || gx >= Ww) {   // OOB col: taps contribute 0 in H
            #pragma unroll
            for (int k = 0; k < 8; ++k) vT[g * 8 + k][c] = make_float2(0.0f, 0.0f);
            continue;
        }
        float2 tt[18]; float ee[18];
        if (yb - MU >= 0 && yb + 13 <= Hh) {
            #pragma unroll
            for (int rr = 0; rr < 18; ++rr) {
                tt[rr] = src[base + (yb - MU + rr) * Ww + gx];
                ee[rr] = eT[8 * g + rr][c];
            }
        } else {
            #pragma unroll
            for (int rr = 0; rr < 18; ++rr) {
                int row = yb - MU + rr;
                bool ok = (row >= 0) && (row < Hh);
                tt[rr] = ok ? src[base + row * Ww + gx] : make_float2(0.0f, 0.0f);
                ee[rr] = ok ? eT[8 * g + rr][c] : 1.0f;
            }
        }
        #pragma unroll
        for (int k = 0; k < 8; ++k) {
            float2 tX = tt[k + MU];
            float  eX = ee[k + MU];
            float ax = 0.0f, ay = 0.0f;
            #pragma unroll
            for (int i = 0; i <= 2 * MU; ++i) {
                float2 tY = tt[k + i];
                float  eY = ee[k + i];
                float d = tX.x * tY.x + tX.y * tY.y;
                float w = eY * rcp_fast(eX + eY) * d;
                ax += tY.x * w;
                ay += tY.y * w;
            }
            vT[g * 8 + k][c] = make_float2(ax, ay);
        }
    }
    __syncthreads();

    // ---- H phase: thread -> row r, 8-px col block cb ----
    int r = t >> 3;               // 0..31
    int cb = (t & 7) * 8;         // 0..56
    float2 wv[18]; float we[18];
    #pragma unroll
    for (int q = 0; q < 18; ++q) {
        wv[q] = vT[r][cb + q];
        we[q] = eT[r + MU][cb + q];
    }
    float ox[8], oy[8];
    #pragma unroll
    for (int j = 0; j < 8; ++j) {
        float2 tX = wv[j + MU];
        float  eX = we[j + MU];
        float ax = 0.0f, ay = 0.0f;
        #pragma unroll
        for (int i = 0; i <= 2 * MU; ++i) {
            float2 tY = wv[j + i];
            float  eY = we[j + i];
            float d = tX.x * tY.x + tX.y * tY.y;
            float w = eY * rcp_fast(eX + eY) * d;
            ax += tY.x * w;
            ay += tY.y * w;
        }
        float n2 = ax * ax + ay * ay;
        float inv = (n2 > 0.0f) ? rsq_fast(n2) : 1.0f;
        ox[j] = ax * inv;
        oy[j] = ay * inv;
    }

    if (FINAL) {
        size_t p0 = ((size_t)(img * 2 + 0) << 20) + (size_t)(y0 + r) * Ww + x0 + cb;
        size_t p1 = ((size_t)(img * 2 + 1) << 20) + (size_t)(y0 + r) * Ww + x0 + cb;
        *(float4*)&dstP[p0]     = make_float4(ox[0], ox[1], ox[2], ox[3]);
        *(float4*)&dstP[p0 + 4] = make_float4(ox[4], ox[5], ox[6], ox[7]);
        *(float4*)&dstP[p1]     = make_float4(oy[0], oy[1], oy[2], oy[3]);
        *(float4*)&dstP[p1 + 4] = make_float4(oy[4], oy[5], oy[6], oy[7]);
    } else {
        // exchange via LDS so global stores are lane-contiguous
        __syncthreads();
        #pragma unroll
        for (int j = 0; j < 8; ++j) vT[r][cb + j] = make_float2(ox[j], oy[j]);
        __syncthreads();
        for (int i = t; i < TY * TX; i += TPB) {
            int rr = i >> 6, cc = i & 63;
            dstI[base + (y0 + rr) * Ww + x0 + cc] = vT[rr][cc];
        }
    }
}

extern "C" void kernel_launch(void* const* d_in, const int* in_sizes, int n_in,
                              void* d_out, int out_size, void* d_ws, size_t ws_size,
                              hipStream_t stream) {
    const float* in = (const float*)d_in[0];
    float* out = (float*)d_out;
    char* ws = (char*)d_ws;

    float* magE = (float*)ws;                                           // 32 MB
    float2* tA = (float2*)(ws + (size_t)NPIX * sizeof(float));          // 64 MB
    float* partials = (float*)(ws + (size_t)NPIX * sizeof(float)
                                  + (size_t)NPIX * sizeof(float2));
    float* scalep = partials + SOBEL_BLOCKS;
    float2* tOut = (float2*)out;

    sobel_kernel<<<SOBEL_BLOCKS, TPB, 0, stream>>>(in, tA, magE, partials);
    max_reduce_kernel<<<1, 1024, 0, stream>>>(partials, scalep);
    prep_kernel<<<NPIX / 4 / TPB, TPB, 0, stream>>>((float4*)magE, scalep);

    // iteration 1: tA -> tOut
    etf_fused<false><<<FBLK, TPB, 0, stream>>>(tA, tOut, nullptr, magE);
    // iteration 2: tOut -> tA
    etf_fused<false><<<FBLK, TPB, 0, stream>>>(tOut, tA, nullptr, magE);
    // iteration 3: tA -> out (planar), no aliasing
    etf_fused<true ><<<FBLK, TPB, 0, stream>>>(tA, nullptr, out, magE);
}